// Round 9
// baseline (1057.301 us; speedup 1.0000x reference)
//
#include <hip/hip_runtime.h>
#include <math.h>

// ---------------------------------------------------------------------------
// TopK graph classifier: 3x (GraphConv -> TopKPool -> readout) + 2x KNN + MLP
// N0=65536,C_IN=64,H=128,E0=524288; pooled 32768/16384/8192; knn k=6 then k=8.
// Round 9:
//  - conv_score v3: 64x128 block / 128 thr / 8x8 tile. LDS 1 B/FMA (was 2),
//    bank-conflict-free by construction (rows ty+8j, cols {tx*4, 64+tx*4}).
//    No register prefetch (r8's 228 VGPR -> occupancy 9.6% regression).
//  - pool de-fused from readout; readout_part 256-block grid-stride +
//    1-block final over 256 partials (was 2048-partial single block).
// ---------------------------------------------------------------------------

namespace {

constexpr int N0 = 65536;
constexpr int C0 = 64;
constexpr int H  = 128;
constexpr int E0 = 524288;
constexpr int N1 = 32768;
constexpr int N2 = 16384;
constexpr int N3 = 8192;
constexpr int G  = 64;      // knn grid dim (positions uniform in [0,1)^2)
constexpr int NC = G * G;   // 4096 cells

// ---------------- utility ----------------
__global__ void fill_zero_kernel(float* __restrict__ p, int n) {
  int i = blockIdx.x * blockDim.x + threadIdx.x;
  if (i < n) p[i] = 0.f;
}

// ---------------- edge counting sort (CSR by dst) --------------------------
__global__ void edge_count_kernel(const int* __restrict__ dst, unsigned* __restrict__ cnt) {
  int e = blockIdx.x * blockDim.x + threadIdx.x;
  if (e < E0) atomicAdd(&cnt[dst[e]], 1u);
}

// exclusive scan of 1024*PER counters; self-cleans cnt.
template<int PER>
__global__ void scan_kernel(unsigned* __restrict__ cnt,
                            unsigned* __restrict__ pre, unsigned* __restrict__ cur) {
  __shared__ unsigned s[1024];
  int t = threadIdx.x;
  unsigned loc[PER];
  unsigned sum = 0;
#pragma unroll
  for (int j = 0; j < PER; ++j) { loc[j] = cnt[t * PER + j]; sum += loc[j]; }
#pragma unroll
  for (int j = 0; j < PER; ++j) cnt[t * PER + j] = 0u;   // self-clean
  s[t] = sum;
  __syncthreads();
  for (int off = 1; off < 1024; off <<= 1) {
    unsigned x = (t >= off) ? s[t - off] : 0u;
    __syncthreads();
    s[t] += x;
    __syncthreads();
  }
  unsigned run = s[t] - sum;
#pragma unroll
  for (int j = 0; j < PER; ++j) {
    pre[t * PER + j] = run;
    cur[t * PER + j] = run;
    run += loc[j];
  }
  if (t == 1023) pre[1024 * PER] = run;
}

__global__ void edge_scatter_kernel(const int* __restrict__ src, const int* __restrict__ dst,
                                    unsigned* __restrict__ cur, int* __restrict__ es) {
  int e = blockIdx.x * blockDim.x + threadIdx.x;
  if (e < E0) {
    unsigned slot = atomicAdd(&cur[dst[e]], 1u);
    es[slot] = src[e];
  }
}

// wave per node; lane f covers feature f (C0=64)
__global__ void gather_agg_kernel(const float* __restrict__ x,
                                  const unsigned* __restrict__ pre,
                                  const int* __restrict__ es,
                                  float* __restrict__ agg) {
  int gid = blockIdx.x * blockDim.x + threadIdx.x;
  int n = gid >> 6, f = gid & 63;
  unsigned s0 = pre[n], s1 = pre[n + 1];
  float v = 0.f;
  for (unsigned j = s0; j < s1; ++j) v += x[(size_t)es[j] * C0 + f];
  agg[(size_t)n * C0 + f] = v;
}

// ---------------- fused conv + score -------------------------------------
// out = relu([agg|x] @ [Wrel;Wroot] + b); score = tanh(out.pw/||pw||) -> key
// Block: 64 rows x 128 cols, 128 threads, 8x8 register tile.
// tx=t&15 (col slot, cols tx*4..+3 and 64+tx*4..+3), ty=t>>4 (rows ty+8j).
// Bank-conflict-free: av reads 4 ty-addrs stride 36 -> disjoint groups;
// wv reads 16 lanes x 16B contiguous (2-way = free).
template<int C>
__global__ __launch_bounds__(128) void conv_score_kernel(
    const float* __restrict__ agg, const float* __restrict__ x,
    const float* __restrict__ Wrel, const float* __restrict__ brel,
    const float* __restrict__ Wroot, const float* __restrict__ pw,
    float* __restrict__ out, unsigned* __restrict__ key,
    unsigned* __restrict__ hist) {
  constexpr int NCH = (2 * C) / 32;   // K' chunks of 32
  __shared__ float sa[64 * 36];       // 64 rows x 32k (pad 36)
  __shared__ float sw[32 * 132];      // 32k x 128 cols (pad 132)
  __shared__ float s_norm;
  int t = threadIdx.x;
  int tx = t & 15;
  int ty = t >> 4;                    // 0..7
  int base = blockIdx.x * 64;

  if (t == 0) s_norm = 0.f;
  __syncthreads();
  {  // ||pw||^2 (128 threads = 2 waves, one value each)
    float v = pw[t];
    float v2 = v * v;
#pragma unroll
    for (int off = 32; off; off >>= 1) v2 += __shfl_down(v2, off);
    if ((t & 63) == 0) atomicAdd(&s_norm, v2);
  }

  float acc[8][8];   // [j][0..3]=cols tx*4.., [j][4..7]=cols 64+tx*4..
  {
    float4 bL = *(const float4*)&brel[tx * 4];
    float4 bR = *(const float4*)&brel[64 + tx * 4];
#pragma unroll
    for (int j = 0; j < 8; ++j) {
      acc[j][0] = bL.x; acc[j][1] = bL.y; acc[j][2] = bL.z; acc[j][3] = bL.w;
      acc[j][4] = bR.x; acc[j][5] = bR.y; acc[j][6] = bR.z; acc[j][7] = bR.w;
    }
  }

  for (int kb = 0; kb < NCH; ++kb) {
    const float* asrc; const float* wsrc; int kg;
    if (kb < NCH / 2) { asrc = agg; wsrc = Wrel;  kg = kb * 32; }
    else              { asrc = x;   wsrc = Wroot; kg = kb * 32 - C; }
    __syncthreads();
    {  // stage A chunk: 64 rows x 32 k; thread: row t>>1, k half (t&1)*16
      int arow = t >> 1, ak0 = (t & 1) * 16;
      const float* g = &asrc[(size_t)(base + arow) * C + kg + ak0];
      float* l = &sa[arow * 36 + ak0];
#pragma unroll
      for (int m = 0; m < 4; ++m) *(float4*)(l + m * 4) = *(const float4*)(g + m * 4);
    }
    {  // stage W chunk: 32 k x 128 cols; thread: k t>>2, col quarter (t&3)*32
      int wk = t >> 2, wc0 = (t & 3) * 32;
      const float* g = &wsrc[(size_t)(kg + wk) * H + wc0];
      float* l = &sw[wk * 132 + wc0];
#pragma unroll
      for (int m = 0; m < 8; ++m) *(float4*)(l + m * 4) = *(const float4*)(g + m * 4);
    }
    __syncthreads();
#pragma unroll
    for (int k4 = 0; k4 < 32; k4 += 4) {
      float4 av[8];
#pragma unroll
      for (int j = 0; j < 8; ++j)
        av[j] = *(const float4*)&sa[(ty + 8 * j) * 36 + k4];
#pragma unroll
      for (int kk = 0; kk < 4; ++kk) {
        float4 wL = *(const float4*)&sw[(k4 + kk) * 132 + tx * 4];
        float4 wR = *(const float4*)&sw[(k4 + kk) * 132 + 64 + tx * 4];
#pragma unroll
        for (int j = 0; j < 8; ++j) {
          float a = ((const float*)&av[j])[kk];
          acc[j][0] += a * wL.x; acc[j][1] += a * wL.y;
          acc[j][2] += a * wL.z; acc[j][3] += a * wL.w;
          acc[j][4] += a * wR.x; acc[j][5] += a * wR.y;
          acc[j][6] += a * wR.z; acc[j][7] += a * wR.w;
        }
      }
    }
  }
  __syncthreads();
  float rn = 1.0f / sqrtf(s_norm);
  float4 pL = *(const float4*)&pw[tx * 4];
  float4 pR = *(const float4*)&pw[64 + tx * 4];
#pragma unroll
  for (int j = 0; j < 8; ++j) {
    int row = base + ty + 8 * j;
    float4 oL, oR;
    oL.x = fmaxf(acc[j][0], 0.f); oL.y = fmaxf(acc[j][1], 0.f);
    oL.z = fmaxf(acc[j][2], 0.f); oL.w = fmaxf(acc[j][3], 0.f);
    oR.x = fmaxf(acc[j][4], 0.f); oR.y = fmaxf(acc[j][5], 0.f);
    oR.z = fmaxf(acc[j][6], 0.f); oR.w = fmaxf(acc[j][7], 0.f);
    *(float4*)&out[(size_t)row * H + tx * 4]      = oL;
    *(float4*)&out[(size_t)row * H + 64 + tx * 4] = oR;
    float d = oL.x * pL.x + oL.y * pL.y + oL.z * pL.z + oL.w * pL.w
            + oR.x * pR.x + oR.y * pR.y + oR.z * pR.z + oR.w * pR.w;
#pragma unroll
    for (int off = 1; off < 16; off <<= 1) d += __shfl_xor(d, off);
    if (tx == 0) {
      float s = tanhf(d * rn);
      unsigned bb = __float_as_uint(s);
      unsigned kv = bb ^ ((unsigned)((int)bb >> 31) | 0x80000000u);
      key[row] = kv;
      atomicAdd(&hist[kv >> 16], 1u);
    }
  }
}

// decode score from key (inverse of the monotonic map)
__device__ inline float key_to_score(unsigned kv) {
  unsigned bb = (kv & 0x80000000u) ? (kv ^ 0x80000000u) : ~kv;
  return __uint_as_float(bb);
}

// ---------------- select pass 1: find high-16 bin; self-clean hist ---------
__global__ void sel_scan1_kernel(unsigned* __restrict__ hist, unsigned* __restrict__ rs, int k) {
  __shared__ unsigned s[1024];
  int t = threadIdx.x;
  unsigned loc[64];
  unsigned sum = 0;
#pragma unroll
  for (int j = 0; j < 64; ++j) { loc[j] = hist[t * 64 + j]; sum += loc[j]; }
#pragma unroll
  for (int j = 0; j < 64; ++j) hist[t * 64 + j] = 0u;  // clean for pass 2
  s[t] = sum;
  __syncthreads();
  for (int off = 1; off < 1024; off <<= 1) {
    unsigned x = (t >= off) ? s[t - off] : 0u;
    __syncthreads();
    s[t] += x;
    __syncthreads();
  }
  unsigned total = s[1023];
  unsigned above = total - s[t];
  if (above < (unsigned)k && above + sum >= (unsigned)k) {
    unsigned cum = above;
    int b = 0; unsigned need = 0;
#pragma unroll
    for (int j = 63; j >= 0; --j) {
      unsigned c = loc[j];
      if (cum + c >= (unsigned)k) { b = t * 64 + j; need = (unsigned)k - cum; break; }
      cum += c;
    }
    rs[0] = (unsigned)b;
    rs[1] = need;
  }
}

__global__ void sel_hist2_kernel(const unsigned* __restrict__ key,
                                 const unsigned* __restrict__ rs,
                                 unsigned* __restrict__ hist, int N) {
  unsigned bhi = rs[0];
  for (int i = blockIdx.x * blockDim.x + threadIdx.x; i < N; i += gridDim.x * blockDim.x) {
    unsigned kv = key[i];
    if ((kv >> 16) == bhi) atomicAdd(&hist[kv & 0xFFFFu], 1u);
  }
}

// self-cleans hist (so next layer's score hist starts from zero)
__global__ void sel_scan2_kernel(unsigned* __restrict__ hist, unsigned* __restrict__ rs) {
  __shared__ unsigned s[1024];
  __shared__ unsigned sh_bhi, sh_need;
  int t = threadIdx.x;
  if (t == 0) { sh_bhi = rs[0]; sh_need = rs[1]; }
  __syncthreads();
  unsigned k = sh_need, bhi = sh_bhi;
  unsigned loc[64];
  unsigned sum = 0;
#pragma unroll
  for (int j = 0; j < 64; ++j) { loc[j] = hist[t * 64 + j]; sum += loc[j]; }
#pragma unroll
  for (int j = 0; j < 64; ++j) hist[t * 64 + j] = 0u;  // self-clean
  s[t] = sum;
  __syncthreads();
  for (int off = 1; off < 1024; off <<= 1) {
    unsigned x = (t >= off) ? s[t - off] : 0u;
    __syncthreads();
    s[t] += x;
    __syncthreads();
  }
  unsigned above = s[1023] - s[t];
  if (above < k && above + sum >= k) {
    unsigned cum = above;
    int b = 0; unsigned need = 0;
#pragma unroll
    for (int j = 63; j >= 0; --j) {
      unsigned c = loc[j];
      if (cum + c >= k) { b = t * 64 + j; need = k - cum; break; }
      cum += c;
    }
    rs[0] = (bhi << 16) | (unsigned)b;
    rs[1] = need;
    rs[2] = 0u;
    rs[3] = 0u;
  }
}

__global__ void sel_compact_kernel(const unsigned* __restrict__ key,
                                   unsigned* __restrict__ rs,
                                   int* __restrict__ perm, int N, int k) {
  unsigned T = rs[0];
  unsigned need = rs[1];
  int base = k - (int)need;
  for (int i = blockIdx.x * blockDim.x + threadIdx.x; i < N; i += gridDim.x * blockDim.x) {
    unsigned kv = key[i];
    if (kv > T) {
      unsigned p = atomicAdd(&rs[2], 1u);
      perm[p] = i;
    } else if (kv == T) {
      unsigned t = atomicAdd(&rs[3], 1u);
      if (t < need) perm[base + (int)t] = i;
    }
  }
}

// ---------------- pool gather + gate + pos + knn cell count ----------------
template<int ROWS, bool CELLS>
__global__ void pool_kernel(const float* __restrict__ xin,
                            const unsigned* __restrict__ key,
                            const int* __restrict__ perm,
                            const float* __restrict__ posin,
                            float* __restrict__ xout, float* __restrict__ posout,
                            unsigned* __restrict__ kcnt, int* __restrict__ kcid) {
  int f = threadIdx.x;  // 128
  int base = blockIdx.x * ROWS;
  for (int r = 0; r < ROWS; ++r) {
    int p = perm[base + r];
    float sc = key_to_score(key[p]);
    float v = xin[(size_t)p * H + f] * sc;
    xout[(size_t)(base + r) * H + f] = v;
    if (f < 2) posout[(base + r) * 2 + f] = posin[p * 2 + f];
    if (CELLS && f == 0) {
      float px = posin[p * 2], py = posin[p * 2 + 1];
      int cx = min(max((int)(px * (float)G), 0), G - 1);
      int cy = min(max((int)(py * (float)G), 0), G - 1);
      int c = cy * G + cx;
      kcid[base + r] = c;
      atomicAdd(&kcnt[c], 1u);
    }
  }
}

// ---------------- readout: per-column max & mean over M rows ----------------
__global__ void readout_part_kernel(const float* __restrict__ x, float* __restrict__ pmax,
                                    float* __restrict__ psum, int M) {
  int f = threadIdx.x;  // 128
  float mx = -INFINITY, sm = 0.f;
  for (int r = blockIdx.x; r < M; r += gridDim.x) {
    float v = x[(size_t)r * H + f];
    mx = fmaxf(mx, v);
    sm += v;
  }
  pmax[blockIdx.x * H + f] = mx;
  psum[blockIdx.x * H + f] = sm;
}

__global__ void readout_final_kernel(const float* __restrict__ pmax,
                                     const float* __restrict__ psum,
                                     float* __restrict__ ha, int M, int nPart, int layer) {
  int f = threadIdx.x;  // 128
  float mx = -INFINITY, sm = 0.f;
  for (int b = 0; b < nPart; ++b) {
    mx = fmaxf(mx, pmax[b * H + f]);
    sm += psum[b * H + f];
  }
  ha[layer * 256 + f]       = mx;
  ha[layer * 256 + 128 + f] = sm / (float)M;
}

// ---------------- KNN via uniform grid (exact) -----------------------------
__global__ void grid_scatter_kernel(const int* __restrict__ cellId,
                                    unsigned* __restrict__ cursor,
                                    int* __restrict__ cellPts, int M) {
  int i = blockIdx.x * blockDim.x + threadIdx.x;
  if (i >= M) return;
  unsigned slot = atomicAdd(&cursor[cellId[i]], 1u);
  cellPts[slot] = i;
}

// queries processed in cell-sorted order for wave coherence + cache locality
template<int K>
__global__ void knn_grid_kernel(const float* __restrict__ pos,
                                const unsigned* __restrict__ pre,
                                const int* __restrict__ cellPts,
                                int* __restrict__ nbr, int M) {
  int s_ = blockIdx.x * blockDim.x + threadIdx.x;
  if (s_ >= M) return;
  int i = cellPts[s_];
  float2 q = reinterpret_cast<const float2*>(pos)[i];
  int cx = min(max((int)(q.x * (float)G), 0), G - 1);
  int cy = min(max((int)(q.y * (float)G), 0), G - 1);
  float bd[K];
  int   bi_[K];
#pragma unroll
  for (int t = 0; t < K; ++t) { bd[t] = INFINITY; bi_[t] = -1; }
  float worst = INFINITY;
  constexpr float cw = 1.0f / (float)G;
  for (int r = 0; r <= G; ++r) {
    if (r > 0) {
      float dl = q.x - (float)(cx - r + 1) * cw;
      float dr = (float)(cx + r) * cw - q.x;
      float db = q.y - (float)(cy - r + 1) * cw;
      float dt = (float)(cy + r) * cw - q.y;
      float m = fminf(fminf(dl, dr), fminf(db, dt));
      if (worst <= m * m) break;
    }
    int xlo = max(cx - r, 0), xhi = min(cx + r, G - 1);
    int ylo = max(cy - r, 0), yhi = min(cy + r, G - 1);
    for (int yy = ylo; yy <= yhi; ++yy) {
      bool yedge = (yy == cy - r) || (yy == cy + r);
      for (int xx = xlo; xx <= xhi; ++xx) {
        if (!yedge && xx != cx - r && xx != cx + r) continue;
        int c = yy * G + xx;
        unsigned s0 = pre[c], s1 = pre[c + 1];
        for (unsigned s = s0; s < s1; ++s) {
          int j = cellPts[s];
          float2 pj = reinterpret_cast<const float2*>(pos)[j];
          float dx = q.x - pj.x, dy = q.y - pj.y;
          float d = dx * dx + dy * dy;
          if (d < worst && j != i) {
            int ws = 0; float wm = bd[0];
#pragma unroll
            for (int t = 1; t < K; ++t) if (bd[t] > wm) { wm = bd[t]; ws = t; }
#pragma unroll
            for (int t = 0; t < K; ++t) {
              bool hit = (t == ws);
              bd[t]  = hit ? d : bd[t];
              bi_[t] = hit ? j : bi_[t];
            }
            float nm = bd[0];
#pragma unroll
            for (int t = 1; t < K; ++t) nm = fmaxf(nm, bd[t]);
            worst = nm;
          }
        }
      }
    }
  }
#pragma unroll
  for (int t = 0; t < K; ++t) nbr[(size_t)i * K + t] = bi_[t];
}

template<int K>
__global__ void knn_agg_kernel(const float* __restrict__ x, const int* __restrict__ nbr,
                               float* __restrict__ agg, int M) {
  int gid = blockIdx.x * blockDim.x + threadIdx.x;
  int i = gid >> 7, f = gid & 127;
  if (i >= M) return;
  float s = 0.f;
#pragma unroll
  for (int j = 0; j < K; ++j) s += x[(size_t)nbr[(size_t)i * K + j] * H + f];
  agg[(size_t)i * H + f] = s;
}

// ---------------- final MLP head (tiny) ------------------------------------
__global__ void mlp_kernel(const float* __restrict__ ha,
                           const float* __restrict__ w1, const float* __restrict__ b1,
                           const float* __restrict__ w2, const float* __restrict__ b2,
                           const float* __restrict__ w3, const float* __restrict__ b3,
                           float* __restrict__ out) {
  __shared__ float h[256], h1[128], h2[64];
  int t = threadIdx.x;
  h[t] = ha[t] + ha[256 + t] + ha[512 + t];
  __syncthreads();
  if (t < 128) {
    float a = b1[t];
    for (int c = 0; c < 256; ++c) a += h[c] * w1[c * 128 + t];
    h1[t] = fmaxf(a, 0.f);
  }
  __syncthreads();
  if (t < 64) {
    float a = b2[t];
    for (int c = 0; c < 128; ++c) a += h1[c] * w2[c * 64 + t];
    h2[t] = fmaxf(a, 0.f);
  }
  __syncthreads();
  if (t < 10) {
    float a = b3[t];
    for (int c = 0; c < 64; ++c) a += h2[c] * w3[c * 10 + t];
    out[t] = a;
  }
}

}  // namespace

extern "C" void kernel_launch(void* const* d_in, const int* in_sizes, int n_in,
                              void* d_out, int out_size, void* d_ws, size_t ws_size,
                              hipStream_t stream) {
  const float* X     = (const float*)d_in[0];   // [N0, C0]
  const float* POS0  = (const float*)d_in[1];   // [N0, 2]
  const int*   EI    = (const int*)d_in[2];     // [2, E0]
  const float* Wrel0 = (const float*)d_in[4];
  const float* brel0 = (const float*)d_in[5];
  const float* Wroot0= (const float*)d_in[6];
  const float* pw0   = (const float*)d_in[7];
  const float* Wrel1 = (const float*)d_in[8];
  const float* brel1 = (const float*)d_in[9];
  const float* Wroot1= (const float*)d_in[10];
  const float* pw1   = (const float*)d_in[11];
  const float* Wrel2 = (const float*)d_in[12];
  const float* brel2 = (const float*)d_in[13];
  const float* Wroot2= (const float*)d_in[14];
  const float* pw2   = (const float*)d_in[15];
  const float* L1W   = (const float*)d_in[16];
  const float* L1B   = (const float*)d_in[17];
  const float* L2W   = (const float*)d_in[18];
  const float* L2B   = (const float*)d_in[19];
  const float* L3W   = (const float*)d_in[20];
  const float* L3B   = (const float*)d_in[21];

  // ---- workspace layout (bytes); ~55.1 MB total; RPm/RPs alias nothing ----
  char* w = (char*)d_ws;
  float*    A    = (float*)(w);                     // 32 MiB: conv out / agg / scratch
  float*    B    = (float*)(w + 33554432u);         // 16 MiB: agg0 / pooled x
  float*    P1   = (float*)(w + 50331648u);         // 256 KB
  float*    P2   = (float*)(w + 50593792u);         // 128 KB
  int*      NBR  = (int*)  (w + 50724864u);         // 768 KB
  unsigned* KY   = (unsigned*)(w + 51511296u);      // 256 KB keys (+ knn pre/cur alias)
  int*      PM   = (int*)  (w + 51773440u);         // 128 KB perm
  unsigned* RS   = (unsigned*)(w + 51904512u);      // 4 KB select state
  unsigned* KCNT = (unsigned*)(w + 51908608u);      // 16 KB knn cell counts
  unsigned* HBUF = (unsigned*)(w + 51924992u);      // 256 KB select hist1/hist2 ONLY
  unsigned* ECNT = (unsigned*)(w + 52187136u);      // 256 KB edge counts / knn cellId
  unsigned* EPRE = (unsigned*)(w + 52449280u);      // 256 KB + 4
  unsigned* ECUR = (unsigned*)(w + 52711936u);      // 256 KB
  float*    RPm  = (float*)(w + 52973568u);         // 128 KB readout partial max (256)
  float*    RPs  = (float*)(w + 54022144u);         // 128 KB readout partial sum
  float*    HA   = (float*)(w + 55070720u);         // 3 KB readout accum [3][256]

  int*      ES    = (int*)A;                        // 2 MB sorted edge src (layer0)
  unsigned* KPRE  = KY;                             // 16 KB + 4 (knn prefix)
  unsigned* KCUR  = KY + 4160;                      // 16 KB (knn cursor)
  int*      KCID  = (int*)ECNT;                     // knn cell ids (edge bufs dead)
  int*      KCPTS = (int*)A;                        // cell-sorted point list

  float* OUT = (float*)d_out;

  // ==================== layer 0 ====================
  // one contiguous zero fill: KCNT(16K) + HBUF(256K) + ECNT(256K) = 528 KB
  fill_zero_kernel<<<528, 256, 0, stream>>>((float*)KCNT, 135168);

  edge_count_kernel<<<E0 / 256, 256, 0, stream>>>(EI + E0, ECNT);
  scan_kernel<64><<<1, 1024, 0, stream>>>(ECNT, EPRE, ECUR);
  edge_scatter_kernel<<<E0 / 256, 256, 0, stream>>>(EI, EI + E0, ECUR, ES);
  gather_agg_kernel<<<(N0 * 64) / 256, 256, 0, stream>>>(X, EPRE, ES, B);

  conv_score_kernel<C0><<<N0 / 64, 128, 0, stream>>>(B, X, Wrel0, brel0, Wroot0,
                                                     pw0, A, KY, HBUF);
  sel_scan1_kernel<<<1, 1024, 0, stream>>>(HBUF, RS, N1);
  sel_hist2_kernel<<<256, 256, 0, stream>>>(KY, RS, HBUF, N0);
  sel_scan2_kernel<<<1, 1024, 0, stream>>>(HBUF, RS);
  sel_compact_kernel<<<256, 256, 0, stream>>>(KY, RS, PM, N0, N1);

  pool_kernel<16, true><<<N1 / 16, 128, 0, stream>>>(
      A, KY, PM, POS0, B, P1, KCNT, KCID);
  readout_part_kernel<<<256, 128, 0, stream>>>(B, RPm, RPs, N1);
  readout_final_kernel<<<1, 128, 0, stream>>>(RPm, RPs, HA, N1, 256, 0);

  scan_kernel<4><<<1, 1024, 0, stream>>>(KCNT, KPRE, KCUR);
  grid_scatter_kernel<<<N1 / 256, 256, 0, stream>>>(KCID, KCUR, KCPTS, N1);
  knn_grid_kernel<6><<<N1 / 64, 64, 0, stream>>>(P1, KPRE, KCPTS, NBR, N1);

  // ==================== layer 1 ====================
  float* AGG1 = A;                       // [N1, H]
  float* CV1  = A + (size_t)N1 * H;      // [N1, H]
  knn_agg_kernel<6><<<(N1 * H) / 256, 256, 0, stream>>>(B, NBR, AGG1, N1);
  conv_score_kernel<H><<<N1 / 64, 128, 0, stream>>>(AGG1, B, Wrel1, brel1, Wroot1,
                                                    pw1, CV1, KY, HBUF);
  sel_scan1_kernel<<<1, 1024, 0, stream>>>(HBUF, RS, N2);
  sel_hist2_kernel<<<256, 256, 0, stream>>>(KY, RS, HBUF, N1);
  sel_scan2_kernel<<<1, 1024, 0, stream>>>(HBUF, RS);
  sel_compact_kernel<<<256, 256, 0, stream>>>(KY, RS, PM, N1, N2);

  pool_kernel<16, true><<<N2 / 16, 128, 0, stream>>>(
      CV1, KY, PM, P1, B, P2, KCNT, KCID);
  readout_part_kernel<<<256, 128, 0, stream>>>(B, RPm, RPs, N2);
  readout_final_kernel<<<1, 128, 0, stream>>>(RPm, RPs, HA, N2, 256, 1);

  scan_kernel<4><<<1, 1024, 0, stream>>>(KCNT, KPRE, KCUR);
  grid_scatter_kernel<<<N2 / 256, 256, 0, stream>>>(KCID, KCUR, KCPTS, N2);
  knn_grid_kernel<8><<<N2 / 64, 64, 0, stream>>>(P2, KPRE, KCPTS, NBR, N2);

  // ==================== layer 2 ====================
  float* AGG2 = A;                       // [N2, H]
  float* CV2  = A + (size_t)N2 * H;      // [N2, H]
  knn_agg_kernel<8><<<(N2 * H) / 256, 256, 0, stream>>>(B, NBR, AGG2, N2);
  conv_score_kernel<H><<<N2 / 64, 128, 0, stream>>>(AGG2, B, Wrel2, brel2, Wroot2,
                                                    pw2, CV2, KY, HBUF);
  sel_scan1_kernel<<<1, 1024, 0, stream>>>(HBUF, RS, N3);
  sel_hist2_kernel<<<256, 256, 0, stream>>>(KY, RS, HBUF, N2);
  sel_scan2_kernel<<<1, 1024, 0, stream>>>(HBUF, RS);
  sel_compact_kernel<<<256, 256, 0, stream>>>(KY, RS, PM, N2, N3);

  // last pool's pos output is never consumed; P1 is dead scratch here
  pool_kernel<16, false><<<N3 / 16, 128, 0, stream>>>(
      CV2, KY, PM, P2, B, P1, KCNT, KCID);
  readout_part_kernel<<<256, 128, 0, stream>>>(B, RPm, RPs, N3);
  readout_final_kernel<<<1, 128, 0, stream>>>(RPm, RPs, HA, N3, 256, 2);

  // ==================== head ====================
  mlp_kernel<<<1, 256, 0, stream>>>(HA, L1W, L1B, L2W, L2B, L3W, L3B, OUT);
}

// Round 10
// 934.785 us; speedup vs baseline: 1.1311x; 1.1311x over previous
//
#include <hip/hip_runtime.h>
#include <math.h>

// ---------------------------------------------------------------------------
// TopK graph classifier: 3x (GraphConv -> TopKPool -> readout) + 2x KNN + MLP
// N0=65536,C_IN=64,H=128,E0=524288; pooled 32768/16384/8192; knn k=6 then k=8.
// Round 10: reassembly of best-measured pieces after r9 regression.
//  - conv: r7's 32-row/256-thr/4x4 variant (79.4us, 44 VGPR, occ 15.5% --
//    best of three measured schedules; r8/r9 variants were equal or worse).
//  - pool/readout: r8's fused pool_readout<16> + 1024-thr final (de-fusion
//    in r9 cost ~95us: extra 17MB pass over B x3 + 6 dispatches).
// ---------------------------------------------------------------------------

namespace {

constexpr int N0 = 65536;
constexpr int C0 = 64;
constexpr int H  = 128;
constexpr int E0 = 524288;
constexpr int N1 = 32768;
constexpr int N2 = 16384;
constexpr int N3 = 8192;
constexpr int G  = 64;      // knn grid dim (positions uniform in [0,1)^2)
constexpr int NC = G * G;   // 4096 cells

// ---------------- utility ----------------
__global__ void fill_zero_kernel(float* __restrict__ p, int n) {
  int i = blockIdx.x * blockDim.x + threadIdx.x;
  if (i < n) p[i] = 0.f;
}

// ---------------- edge counting sort (CSR by dst) --------------------------
__global__ void edge_count_kernel(const int* __restrict__ dst, unsigned* __restrict__ cnt) {
  int e = blockIdx.x * blockDim.x + threadIdx.x;
  if (e < E0) atomicAdd(&cnt[dst[e]], 1u);
}

// exclusive scan of 1024*PER counters; self-cleans cnt.
template<int PER>
__global__ void scan_kernel(unsigned* __restrict__ cnt,
                            unsigned* __restrict__ pre, unsigned* __restrict__ cur) {
  __shared__ unsigned s[1024];
  int t = threadIdx.x;
  unsigned loc[PER];
  unsigned sum = 0;
#pragma unroll
  for (int j = 0; j < PER; ++j) { loc[j] = cnt[t * PER + j]; sum += loc[j]; }
#pragma unroll
  for (int j = 0; j < PER; ++j) cnt[t * PER + j] = 0u;   // self-clean
  s[t] = sum;
  __syncthreads();
  for (int off = 1; off < 1024; off <<= 1) {
    unsigned x = (t >= off) ? s[t - off] : 0u;
    __syncthreads();
    s[t] += x;
    __syncthreads();
  }
  unsigned run = s[t] - sum;
#pragma unroll
  for (int j = 0; j < PER; ++j) {
    pre[t * PER + j] = run;
    cur[t * PER + j] = run;
    run += loc[j];
  }
  if (t == 1023) pre[1024 * PER] = run;
}

__global__ void edge_scatter_kernel(const int* __restrict__ src, const int* __restrict__ dst,
                                    unsigned* __restrict__ cur, int* __restrict__ es) {
  int e = blockIdx.x * blockDim.x + threadIdx.x;
  if (e < E0) {
    unsigned slot = atomicAdd(&cur[dst[e]], 1u);
    es[slot] = src[e];
  }
}

// wave per node; lane f covers feature f (C0=64)
__global__ void gather_agg_kernel(const float* __restrict__ x,
                                  const unsigned* __restrict__ pre,
                                  const int* __restrict__ es,
                                  float* __restrict__ agg) {
  int gid = blockIdx.x * blockDim.x + threadIdx.x;
  int n = gid >> 6, f = gid & 63;
  unsigned s0 = pre[n], s1 = pre[n + 1];
  float v = 0.f;
  for (unsigned j = s0; j < s1; ++j) v += x[(size_t)es[j] * C0 + f];
  agg[(size_t)n * C0 + f] = v;
}

// ---------------- fused conv + score (r7's proven variant) -----------------
// out = relu([agg|x] @ [Wrel;Wroot] + b); score = tanh(out.pw/||pw||) -> key
// Block: 32 rows x 128 cols, 256 threads, 4x4 register tile per thread.
template<int C>
__global__ __launch_bounds__(256) void conv_score_kernel(
    const float* __restrict__ agg, const float* __restrict__ x,
    const float* __restrict__ Wrel, const float* __restrict__ brel,
    const float* __restrict__ Wroot, const float* __restrict__ pw,
    float* __restrict__ out, unsigned* __restrict__ key,
    unsigned* __restrict__ hist) {
  constexpr int NCH = (2 * C) / 32;   // K' chunks of 32
  __shared__ float sa[32 * 36];       // 32 rows x 32k (pad 36)
  __shared__ float sw[32 * 132];      // 32k x 128 cols (pad 132)
  __shared__ float s_norm;
  int t = threadIdx.x;
  int tx = t & 31;
  int ty = t >> 5;
  int base = blockIdx.x * 32;

  if (t == 0) s_norm = 0.f;
  __syncthreads();
  {  // ||pw||^2: waves 0,1 hold the 128 pw values
    float v = (t < 128) ? pw[t] : 0.f;
    float v2 = v * v;
#pragma unroll
    for (int off = 32; off; off >>= 1) v2 += __shfl_down(v2, off);
    if ((t & 63) == 0 && t < 128) atomicAdd(&s_norm, v2);
  }

  float acc[4][4];
  {
    float4 b = *(const float4*)&brel[tx * 4];
#pragma unroll
    for (int j = 0; j < 4; ++j) {
      acc[j][0] = b.x; acc[j][1] = b.y; acc[j][2] = b.z; acc[j][3] = b.w;
    }
  }

  for (int kb = 0; kb < NCH; ++kb) {
    const float* asrc; const float* wsrc; int kg;
    if (kb < NCH / 2) { asrc = agg; wsrc = Wrel;  kg = kb * 32; }
    else              { asrc = x;   wsrc = Wroot; kg = kb * 32 - C; }
    __syncthreads();
    {  // stage A chunk: 32 rows x 32 k; each thread one float4
      int row = t >> 3, k0 = (t & 7) * 4;
      *(float4*)&sa[row * 36 + k0] =
          *(const float4*)&asrc[(size_t)(base + row) * C + kg + k0];
    }
    {  // stage W chunk: 32 k x 128 cols; each thread four float4
      int k = t >> 3, c0 = (t & 7) * 16;
      const float* g = &wsrc[(size_t)(kg + k) * H + c0];
      float* l = &sw[k * 132 + c0];
#pragma unroll
      for (int m = 0; m < 4; ++m) *(float4*)(l + m * 4) = *(const float4*)(g + m * 4);
    }
    __syncthreads();
#pragma unroll
    for (int k4 = 0; k4 < 32; k4 += 4) {
      float4 av[4];
      av[0] = *(const float4*)&sa[(ty)      * 36 + k4];
      av[1] = *(const float4*)&sa[(ty + 8)  * 36 + k4];
      av[2] = *(const float4*)&sa[(ty + 16) * 36 + k4];
      av[3] = *(const float4*)&sa[(ty + 24) * 36 + k4];
#pragma unroll
      for (int kk = 0; kk < 4; ++kk) {
        float4 wv = *(const float4*)&sw[(k4 + kk) * 132 + tx * 4];
#pragma unroll
        for (int j = 0; j < 4; ++j) {
          float a = ((const float*)&av[j])[kk];
          acc[j][0] += a * wv.x; acc[j][1] += a * wv.y;
          acc[j][2] += a * wv.z; acc[j][3] += a * wv.w;
        }
      }
    }
  }
  __syncthreads();
  float rn = 1.0f / sqrtf(s_norm);
  float4 p = *(const float4*)&pw[tx * 4];
#pragma unroll
  for (int j = 0; j < 4; ++j) {
    int row = base + ty + 8 * j;
    float4 o;
    o.x = fmaxf(acc[j][0], 0.f); o.y = fmaxf(acc[j][1], 0.f);
    o.z = fmaxf(acc[j][2], 0.f); o.w = fmaxf(acc[j][3], 0.f);
    *(float4*)&out[(size_t)row * H + tx * 4] = o;
    float d = o.x * p.x + o.y * p.y + o.z * p.z + o.w * p.w;
#pragma unroll
    for (int off = 1; off < 32; off <<= 1) d += __shfl_xor(d, off);
    if (tx == 0) {
      float s = tanhf(d * rn);
      unsigned bb = __float_as_uint(s);
      unsigned kv = bb ^ ((unsigned)((int)bb >> 31) | 0x80000000u);
      key[row] = kv;
      atomicAdd(&hist[kv >> 16], 1u);
    }
  }
}

// decode score from key (inverse of the monotonic map)
__device__ inline float key_to_score(unsigned kv) {
  unsigned bb = (kv & 0x80000000u) ? (kv ^ 0x80000000u) : ~kv;
  return __uint_as_float(bb);
}

// ---------------- select pass 1: find high-16 bin; self-clean hist ---------
__global__ void sel_scan1_kernel(unsigned* __restrict__ hist, unsigned* __restrict__ rs, int k) {
  __shared__ unsigned s[1024];
  int t = threadIdx.x;
  unsigned loc[64];
  unsigned sum = 0;
#pragma unroll
  for (int j = 0; j < 64; ++j) { loc[j] = hist[t * 64 + j]; sum += loc[j]; }
#pragma unroll
  for (int j = 0; j < 64; ++j) hist[t * 64 + j] = 0u;  // clean for pass 2
  s[t] = sum;
  __syncthreads();
  for (int off = 1; off < 1024; off <<= 1) {
    unsigned x = (t >= off) ? s[t - off] : 0u;
    __syncthreads();
    s[t] += x;
    __syncthreads();
  }
  unsigned total = s[1023];
  unsigned above = total - s[t];
  if (above < (unsigned)k && above + sum >= (unsigned)k) {
    unsigned cum = above;
    int b = 0; unsigned need = 0;
#pragma unroll
    for (int j = 63; j >= 0; --j) {
      unsigned c = loc[j];
      if (cum + c >= (unsigned)k) { b = t * 64 + j; need = (unsigned)k - cum; break; }
      cum += c;
    }
    rs[0] = (unsigned)b;
    rs[1] = need;
  }
}

__global__ void sel_hist2_kernel(const unsigned* __restrict__ key,
                                 const unsigned* __restrict__ rs,
                                 unsigned* __restrict__ hist, int N) {
  unsigned bhi = rs[0];
  for (int i = blockIdx.x * blockDim.x + threadIdx.x; i < N; i += gridDim.x * blockDim.x) {
    unsigned kv = key[i];
    if ((kv >> 16) == bhi) atomicAdd(&hist[kv & 0xFFFFu], 1u);
  }
}

// self-cleans hist (so next layer's score hist starts from zero)
__global__ void sel_scan2_kernel(unsigned* __restrict__ hist, unsigned* __restrict__ rs) {
  __shared__ unsigned s[1024];
  __shared__ unsigned sh_bhi, sh_need;
  int t = threadIdx.x;
  if (t == 0) { sh_bhi = rs[0]; sh_need = rs[1]; }
  __syncthreads();
  unsigned k = sh_need, bhi = sh_bhi;
  unsigned loc[64];
  unsigned sum = 0;
#pragma unroll
  for (int j = 0; j < 64; ++j) { loc[j] = hist[t * 64 + j]; sum += loc[j]; }
#pragma unroll
  for (int j = 0; j < 64; ++j) hist[t * 64 + j] = 0u;  // self-clean
  s[t] = sum;
  __syncthreads();
  for (int off = 1; off < 1024; off <<= 1) {
    unsigned x = (t >= off) ? s[t - off] : 0u;
    __syncthreads();
    s[t] += x;
    __syncthreads();
  }
  unsigned above = s[1023] - s[t];
  if (above < k && above + sum >= k) {
    unsigned cum = above;
    int b = 0; unsigned need = 0;
#pragma unroll
    for (int j = 63; j >= 0; --j) {
      unsigned c = loc[j];
      if (cum + c >= k) { b = t * 64 + j; need = k - cum; break; }
      cum += c;
    }
    rs[0] = (bhi << 16) | (unsigned)b;
    rs[1] = need;
    rs[2] = 0u;
    rs[3] = 0u;
  }
}

__global__ void sel_compact_kernel(const unsigned* __restrict__ key,
                                   unsigned* __restrict__ rs,
                                   int* __restrict__ perm, int N, int k) {
  unsigned T = rs[0];
  unsigned need = rs[1];
  int base = k - (int)need;
  for (int i = blockIdx.x * blockDim.x + threadIdx.x; i < N; i += gridDim.x * blockDim.x) {
    unsigned kv = key[i];
    if (kv > T) {
      unsigned p = atomicAdd(&rs[2], 1u);
      perm[p] = i;
    } else if (kv == T) {
      unsigned t = atomicAdd(&rs[3], 1u);
      if (t < need) perm[base + (int)t] = i;
    }
  }
}

// ---------------- pool gather + gate + pos + readout + knn cell count ------
template<int ROWS, bool CELLS>
__global__ void pool_readout_kernel(const float* __restrict__ xin,
                                    const unsigned* __restrict__ key,
                                    const int* __restrict__ perm,
                                    const float* __restrict__ posin,
                                    float* __restrict__ xout, float* __restrict__ posout,
                                    float* __restrict__ pmax, float* __restrict__ psum,
                                    unsigned* __restrict__ kcnt, int* __restrict__ kcid) {
  int f = threadIdx.x;  // 128
  int base = blockIdx.x * ROWS;
  float mx = -INFINITY, sm = 0.f;
  for (int r = 0; r < ROWS; ++r) {
    int p = perm[base + r];
    float sc = key_to_score(key[p]);
    float v = xin[(size_t)p * H + f] * sc;
    xout[(size_t)(base + r) * H + f] = v;
    mx = fmaxf(mx, v);
    sm += v;
    if (f < 2) posout[(base + r) * 2 + f] = posin[p * 2 + f];
    if (CELLS && f == 0) {
      float px = posin[p * 2], py = posin[p * 2 + 1];
      int cx = min(max((int)(px * (float)G), 0), G - 1);
      int cy = min(max((int)(py * (float)G), 0), G - 1);
      int c = cy * G + cx;
      kcid[base + r] = c;
      atomicAdd(&kcnt[c], 1u);
    }
  }
  pmax[blockIdx.x * H + f] = mx;
  psum[blockIdx.x * H + f] = sm;
}

// 1024 threads: f = t&127, chunk = t>>7 over nPart partials; LDS combine.
__global__ void readout_final_kernel(const float* __restrict__ pmax,
                                     const float* __restrict__ psum,
                                     float* __restrict__ ha, int M, int nPart, int layer) {
  __shared__ float smx[1024], ssm[1024];
  int t = threadIdx.x;
  int f = t & 127;
  int c = t >> 7;       // 0..7
  int per = nPart >> 3; // nPart/8
  float mx = -INFINITY, sm = 0.f;
  for (int b = c * per; b < (c + 1) * per; ++b) {
    mx = fmaxf(mx, pmax[b * H + f]);
    sm += psum[b * H + f];
  }
  smx[t] = mx; ssm[t] = sm;
  __syncthreads();
  if (t < 128) {
#pragma unroll
    for (int c2 = 1; c2 < 8; ++c2) {
      mx = fmaxf(mx, smx[t + 128 * c2]);
      sm += ssm[t + 128 * c2];
    }
    ha[layer * 256 + f]       = mx;
    ha[layer * 256 + 128 + f] = sm / (float)M;
  }
}

// ---------------- KNN via uniform grid (exact) -----------------------------
__global__ void grid_scatter_kernel(const int* __restrict__ cellId,
                                    unsigned* __restrict__ cursor,
                                    int* __restrict__ cellPts, int M) {
  int i = blockIdx.x * blockDim.x + threadIdx.x;
  if (i >= M) return;
  unsigned slot = atomicAdd(&cursor[cellId[i]], 1u);
  cellPts[slot] = i;
}

// queries processed in cell-sorted order for wave coherence + cache locality
template<int K>
__global__ void knn_grid_kernel(const float* __restrict__ pos,
                                const unsigned* __restrict__ pre,
                                const int* __restrict__ cellPts,
                                int* __restrict__ nbr, int M) {
  int s_ = blockIdx.x * blockDim.x + threadIdx.x;
  if (s_ >= M) return;
  int i = cellPts[s_];
  float2 q = reinterpret_cast<const float2*>(pos)[i];
  int cx = min(max((int)(q.x * (float)G), 0), G - 1);
  int cy = min(max((int)(q.y * (float)G), 0), G - 1);
  float bd[K];
  int   bi_[K];
#pragma unroll
  for (int t = 0; t < K; ++t) { bd[t] = INFINITY; bi_[t] = -1; }
  float worst = INFINITY;
  constexpr float cw = 1.0f / (float)G;
  for (int r = 0; r <= G; ++r) {
    if (r > 0) {
      float dl = q.x - (float)(cx - r + 1) * cw;
      float dr = (float)(cx + r) * cw - q.x;
      float db = q.y - (float)(cy - r + 1) * cw;
      float dt = (float)(cy + r) * cw - q.y;
      float m = fminf(fminf(dl, dr), fminf(db, dt));
      if (worst <= m * m) break;
    }
    int xlo = max(cx - r, 0), xhi = min(cx + r, G - 1);
    int ylo = max(cy - r, 0), yhi = min(cy + r, G - 1);
    for (int yy = ylo; yy <= yhi; ++yy) {
      bool yedge = (yy == cy - r) || (yy == cy + r);
      for (int xx = xlo; xx <= xhi; ++xx) {
        if (!yedge && xx != cx - r && xx != cx + r) continue;
        int c = yy * G + xx;
        unsigned s0 = pre[c], s1 = pre[c + 1];
        for (unsigned s = s0; s < s1; ++s) {
          int j = cellPts[s];
          float2 pj = reinterpret_cast<const float2*>(pos)[j];
          float dx = q.x - pj.x, dy = q.y - pj.y;
          float d = dx * dx + dy * dy;
          if (d < worst && j != i) {
            int ws = 0; float wm = bd[0];
#pragma unroll
            for (int t = 1; t < K; ++t) if (bd[t] > wm) { wm = bd[t]; ws = t; }
#pragma unroll
            for (int t = 0; t < K; ++t) {
              bool hit = (t == ws);
              bd[t]  = hit ? d : bd[t];
              bi_[t] = hit ? j : bi_[t];
            }
            float nm = bd[0];
#pragma unroll
            for (int t = 1; t < K; ++t) nm = fmaxf(nm, bd[t]);
            worst = nm;
          }
        }
      }
    }
  }
#pragma unroll
  for (int t = 0; t < K; ++t) nbr[(size_t)i * K + t] = bi_[t];
}

template<int K>
__global__ void knn_agg_kernel(const float* __restrict__ x, const int* __restrict__ nbr,
                               float* __restrict__ agg, int M) {
  int gid = blockIdx.x * blockDim.x + threadIdx.x;
  int i = gid >> 7, f = gid & 127;
  if (i >= M) return;
  float s = 0.f;
#pragma unroll
  for (int j = 0; j < K; ++j) s += x[(size_t)nbr[(size_t)i * K + j] * H + f];
  agg[(size_t)i * H + f] = s;
}

// ---------------- final MLP head (tiny) ------------------------------------
__global__ void mlp_kernel(const float* __restrict__ ha,
                           const float* __restrict__ w1, const float* __restrict__ b1,
                           const float* __restrict__ w2, const float* __restrict__ b2,
                           const float* __restrict__ w3, const float* __restrict__ b3,
                           float* __restrict__ out) {
  __shared__ float h[256], h1[128], h2[64];
  int t = threadIdx.x;
  h[t] = ha[t] + ha[256 + t] + ha[512 + t];
  __syncthreads();
  if (t < 128) {
    float a = b1[t];
    for (int c = 0; c < 256; ++c) a += h[c] * w1[c * 128 + t];
    h1[t] = fmaxf(a, 0.f);
  }
  __syncthreads();
  if (t < 64) {
    float a = b2[t];
    for (int c = 0; c < 128; ++c) a += h1[c] * w2[c * 64 + t];
    h2[t] = fmaxf(a, 0.f);
  }
  __syncthreads();
  if (t < 10) {
    float a = b3[t];
    for (int c = 0; c < 64; ++c) a += h2[c] * w3[c * 10 + t];
    out[t] = a;
  }
}

}  // namespace

extern "C" void kernel_launch(void* const* d_in, const int* in_sizes, int n_in,
                              void* d_out, int out_size, void* d_ws, size_t ws_size,
                              hipStream_t stream) {
  const float* X     = (const float*)d_in[0];   // [N0, C0]
  const float* POS0  = (const float*)d_in[1];   // [N0, 2]
  const int*   EI    = (const int*)d_in[2];     // [2, E0]
  const float* Wrel0 = (const float*)d_in[4];
  const float* brel0 = (const float*)d_in[5];
  const float* Wroot0= (const float*)d_in[6];
  const float* pw0   = (const float*)d_in[7];
  const float* Wrel1 = (const float*)d_in[8];
  const float* brel1 = (const float*)d_in[9];
  const float* Wroot1= (const float*)d_in[10];
  const float* pw1   = (const float*)d_in[11];
  const float* Wrel2 = (const float*)d_in[12];
  const float* brel2 = (const float*)d_in[13];
  const float* Wroot2= (const float*)d_in[14];
  const float* pw2   = (const float*)d_in[15];
  const float* L1W   = (const float*)d_in[16];
  const float* L1B   = (const float*)d_in[17];
  const float* L2W   = (const float*)d_in[18];
  const float* L2B   = (const float*)d_in[19];
  const float* L3W   = (const float*)d_in[20];
  const float* L3B   = (const float*)d_in[21];

  // ---- workspace layout (bytes); ~55.1 MB total; RPm/RPs alias nothing ----
  char* w = (char*)d_ws;
  float*    A    = (float*)(w);                     // 32 MiB: conv out / agg / scratch
  float*    B    = (float*)(w + 33554432u);         // 16 MiB: agg0 / pooled x
  float*    P1   = (float*)(w + 50331648u);         // 256 KB
  float*    P2   = (float*)(w + 50593792u);         // 128 KB
  int*      NBR  = (int*)  (w + 50724864u);         // 768 KB
  unsigned* KY   = (unsigned*)(w + 51511296u);      // 256 KB keys (+ knn pre/cur alias)
  int*      PM   = (int*)  (w + 51773440u);         // 128 KB perm
  unsigned* RS   = (unsigned*)(w + 51904512u);      // 4 KB select state
  unsigned* KCNT = (unsigned*)(w + 51908608u);      // 16 KB knn cell counts
  unsigned* HBUF = (unsigned*)(w + 51924992u);      // 256 KB select hist1/hist2 ONLY
  unsigned* ECNT = (unsigned*)(w + 52187136u);      // 256 KB edge counts / knn cellId
  unsigned* EPRE = (unsigned*)(w + 52449280u);      // 256 KB + 4
  unsigned* ECUR = (unsigned*)(w + 52711936u);      // 256 KB
  float*    RPm  = (float*)(w + 52973568u);         // 1 MB readout partial max (<=2048)
  float*    RPs  = (float*)(w + 54022144u);         // 1 MB readout partial sum
  float*    HA   = (float*)(w + 55070720u);         // 3 KB readout accum [3][256]

  int*      ES    = (int*)A;                        // 2 MB sorted edge src (layer0)
  unsigned* KPRE  = KY;                             // 16 KB + 4 (knn prefix)
  unsigned* KCUR  = KY + 4160;                      // 16 KB (knn cursor)
  int*      KCID  = (int*)ECNT;                     // knn cell ids (edge bufs dead)
  int*      KCPTS = (int*)A;                        // cell-sorted point list

  float* OUT = (float*)d_out;

  // ==================== layer 0 ====================
  // one contiguous zero fill: KCNT(16K) + HBUF(256K) + ECNT(256K) = 528 KB
  fill_zero_kernel<<<528, 256, 0, stream>>>((float*)KCNT, 135168);

  edge_count_kernel<<<E0 / 256, 256, 0, stream>>>(EI + E0, ECNT);
  scan_kernel<64><<<1, 1024, 0, stream>>>(ECNT, EPRE, ECUR);
  edge_scatter_kernel<<<E0 / 256, 256, 0, stream>>>(EI, EI + E0, ECUR, ES);
  gather_agg_kernel<<<(N0 * 64) / 256, 256, 0, stream>>>(X, EPRE, ES, B);

  conv_score_kernel<C0><<<N0 / 32, 256, 0, stream>>>(B, X, Wrel0, brel0, Wroot0,
                                                     pw0, A, KY, HBUF);
  sel_scan1_kernel<<<1, 1024, 0, stream>>>(HBUF, RS, N1);
  sel_hist2_kernel<<<256, 256, 0, stream>>>(KY, RS, HBUF, N0);
  sel_scan2_kernel<<<1, 1024, 0, stream>>>(HBUF, RS);
  sel_compact_kernel<<<256, 256, 0, stream>>>(KY, RS, PM, N0, N1);

  pool_readout_kernel<16, true><<<N1 / 16, 128, 0, stream>>>(
      A, KY, PM, POS0, B, P1, RPm, RPs, KCNT, KCID);
  readout_final_kernel<<<1, 1024, 0, stream>>>(RPm, RPs, HA, N1, N1 / 16, 0);

  scan_kernel<4><<<1, 1024, 0, stream>>>(KCNT, KPRE, KCUR);
  grid_scatter_kernel<<<N1 / 256, 256, 0, stream>>>(KCID, KCUR, KCPTS, N1);
  knn_grid_kernel<6><<<N1 / 64, 64, 0, stream>>>(P1, KPRE, KCPTS, NBR, N1);

  // ==================== layer 1 ====================
  float* AGG1 = A;                       // [N1, H]
  float* CV1  = A + (size_t)N1 * H;      // [N1, H]
  knn_agg_kernel<6><<<(N1 * H) / 256, 256, 0, stream>>>(B, NBR, AGG1, N1);
  conv_score_kernel<H><<<N1 / 32, 256, 0, stream>>>(AGG1, B, Wrel1, brel1, Wroot1,
                                                    pw1, CV1, KY, HBUF);
  sel_scan1_kernel<<<1, 1024, 0, stream>>>(HBUF, RS, N2);
  sel_hist2_kernel<<<256, 256, 0, stream>>>(KY, RS, HBUF, N1);
  sel_scan2_kernel<<<1, 1024, 0, stream>>>(HBUF, RS);
  sel_compact_kernel<<<256, 256, 0, stream>>>(KY, RS, PM, N1, N2);

  pool_readout_kernel<16, true><<<N2 / 16, 128, 0, stream>>>(
      CV1, KY, PM, P1, B, P2, RPm, RPs, KCNT, KCID);
  readout_final_kernel<<<1, 1024, 0, stream>>>(RPm, RPs, HA, N2, N2 / 16, 1);

  scan_kernel<4><<<1, 1024, 0, stream>>>(KCNT, KPRE, KCUR);
  grid_scatter_kernel<<<N2 / 256, 256, 0, stream>>>(KCID, KCUR, KCPTS, N2);
  knn_grid_kernel<8><<<N2 / 64, 64, 0, stream>>>(P2, KPRE, KCPTS, NBR, N2);

  // ==================== layer 2 ====================
  float* AGG2 = A;                       // [N2, H]
  float* CV2  = A + (size_t)N2 * H;      // [N2, H]
  knn_agg_kernel<8><<<(N2 * H) / 256, 256, 0, stream>>>(B, NBR, AGG2, N2);
  conv_score_kernel<H><<<N2 / 32, 256, 0, stream>>>(AGG2, B, Wrel2, brel2, Wroot2,
                                                    pw2, CV2, KY, HBUF);
  sel_scan1_kernel<<<1, 1024, 0, stream>>>(HBUF, RS, N3);
  sel_hist2_kernel<<<256, 256, 0, stream>>>(KY, RS, HBUF, N2);
  sel_scan2_kernel<<<1, 1024, 0, stream>>>(HBUF, RS);
  sel_compact_kernel<<<256, 256, 0, stream>>>(KY, RS, PM, N2, N3);

  // last pool's pos output is never consumed; P1 is dead scratch here
  pool_readout_kernel<16, false><<<N3 / 16, 128, 0, stream>>>(
      CV2, KY, PM, P2, B, P1, RPm, RPs, KCNT, KCID);
  readout_final_kernel<<<1, 1024, 0, stream>>>(RPm, RPs, HA, N3, N3 / 16, 2);

  // ==================== head ====================
  mlp_kernel<<<1, 256, 0, stream>>>(HA, L1W, L1B, L2W, L2B, L3W, L3B, OUT);
}

// Round 13
// 814.644 us; speedup vs baseline: 1.2979x; 1.1475x over previous
//
#include <hip/hip_runtime.h>
#include <math.h>

// ---------------------------------------------------------------------------
// TopK graph classifier: 3x (GraphConv -> TopKPool -> readout) + 2x KNN + MLP
// N0=65536,C_IN=64,H=128,E0=524288; pooled 32768/16384/8192; knn k=6 then k=8.
// Round 13 (second resubmit of r11; r11 and r12 both hit broker/infra
// failures and never executed): kill the 84us single-block readout_final
// (2MB through 1 CU = 24 GB/s, 252us total). Replaced by 256-block
// readout_atomic: local reduce + atomicMax(monotonic-uint) /
// atomicAdd(float) into [3][128] accumulators; MLP head decodes + applies
// 1/M. conv/pool/select/knn unchanged from r10 (935us measured).
// ---------------------------------------------------------------------------

namespace {

constexpr int N0 = 65536;
constexpr int C0 = 64;
constexpr int H  = 128;
constexpr int E0 = 524288;
constexpr int N1 = 32768;
constexpr int N2 = 16384;
constexpr int N3 = 8192;
constexpr int G  = 64;      // knn grid dim (positions uniform in [0,1)^2)
constexpr int NC = G * G;   // 4096 cells

__device__ inline unsigned map_f2u(float s) {
  unsigned bb = __float_as_uint(s);
  return bb ^ ((unsigned)((int)bb >> 31) | 0x80000000u);
}
__device__ inline float map_u2f(unsigned kv) {
  unsigned bb = (kv & 0x80000000u) ? (kv ^ 0x80000000u) : ~kv;
  return __uint_as_float(bb);
}

// ---------------- utility ----------------
__global__ void fill_zero_kernel(float* __restrict__ p, int n) {
  int i = blockIdx.x * blockDim.x + threadIdx.x;
  if (i < n) p[i] = 0.f;
}

// ---------------- edge counting sort (CSR by dst) --------------------------
__global__ void edge_count_kernel(const int* __restrict__ dst, unsigned* __restrict__ cnt) {
  int e = blockIdx.x * blockDim.x + threadIdx.x;
  if (e < E0) atomicAdd(&cnt[dst[e]], 1u);
}

// exclusive scan of 1024*PER counters; self-cleans cnt.
template<int PER>
__global__ void scan_kernel(unsigned* __restrict__ cnt,
                            unsigned* __restrict__ pre, unsigned* __restrict__ cur) {
  __shared__ unsigned s[1024];
  int t = threadIdx.x;
  unsigned loc[PER];
  unsigned sum = 0;
#pragma unroll
  for (int j = 0; j < PER; ++j) { loc[j] = cnt[t * PER + j]; sum += loc[j]; }
#pragma unroll
  for (int j = 0; j < PER; ++j) cnt[t * PER + j] = 0u;   // self-clean
  s[t] = sum;
  __syncthreads();
  for (int off = 1; off < 1024; off <<= 1) {
    unsigned x = (t >= off) ? s[t - off] : 0u;
    __syncthreads();
    s[t] += x;
    __syncthreads();
  }
  unsigned run = s[t] - sum;
#pragma unroll
  for (int j = 0; j < PER; ++j) {
    pre[t * PER + j] = run;
    cur[t * PER + j] = run;
    run += loc[j];
  }
  if (t == 1023) pre[1024 * PER] = run;
}

__global__ void edge_scatter_kernel(const int* __restrict__ src, const int* __restrict__ dst,
                                    unsigned* __restrict__ cur, int* __restrict__ es) {
  int e = blockIdx.x * blockDim.x + threadIdx.x;
  if (e < E0) {
    unsigned slot = atomicAdd(&cur[dst[e]], 1u);
    es[slot] = src[e];
  }
}

// wave per node; lane f covers feature f (C0=64)
__global__ void gather_agg_kernel(const float* __restrict__ x,
                                  const unsigned* __restrict__ pre,
                                  const int* __restrict__ es,
                                  float* __restrict__ agg) {
  int gid = blockIdx.x * blockDim.x + threadIdx.x;
  int n = gid >> 6, f = gid & 63;
  unsigned s0 = pre[n], s1 = pre[n + 1];
  float v = 0.f;
  for (unsigned j = s0; j < s1; ++j) v += x[(size_t)es[j] * C0 + f];
  agg[(size_t)n * C0 + f] = v;
}

// ---------------- fused conv + score (r7's proven variant) -----------------
// out = relu([agg|x] @ [Wrel;Wroot] + b); score = tanh(out.pw/||pw||) -> key
// Block: 32 rows x 128 cols, 256 threads, 4x4 register tile per thread.
template<int C>
__global__ __launch_bounds__(256) void conv_score_kernel(
    const float* __restrict__ agg, const float* __restrict__ x,
    const float* __restrict__ Wrel, const float* __restrict__ brel,
    const float* __restrict__ Wroot, const float* __restrict__ pw,
    float* __restrict__ out, unsigned* __restrict__ key,
    unsigned* __restrict__ hist) {
  constexpr int NCH = (2 * C) / 32;   // K' chunks of 32
  __shared__ float sa[32 * 36];       // 32 rows x 32k (pad 36)
  __shared__ float sw[32 * 132];      // 32k x 128 cols (pad 132)
  __shared__ float s_norm;
  int t = threadIdx.x;
  int tx = t & 31;
  int ty = t >> 5;
  int base = blockIdx.x * 32;

  if (t == 0) s_norm = 0.f;
  __syncthreads();
  {  // ||pw||^2: waves 0,1 hold the 128 pw values
    float v = (t < 128) ? pw[t] : 0.f;
    float v2 = v * v;
#pragma unroll
    for (int off = 32; off; off >>= 1) v2 += __shfl_down(v2, off);
    if ((t & 63) == 0 && t < 128) atomicAdd(&s_norm, v2);
  }

  float acc[4][4];
  {
    float4 b = *(const float4*)&brel[tx * 4];
#pragma unroll
    for (int j = 0; j < 4; ++j) {
      acc[j][0] = b.x; acc[j][1] = b.y; acc[j][2] = b.z; acc[j][3] = b.w;
    }
  }

  for (int kb = 0; kb < NCH; ++kb) {
    const float* asrc; const float* wsrc; int kg;
    if (kb < NCH / 2) { asrc = agg; wsrc = Wrel;  kg = kb * 32; }
    else              { asrc = x;   wsrc = Wroot; kg = kb * 32 - C; }
    __syncthreads();
    {  // stage A chunk: 32 rows x 32 k; each thread one float4
      int row = t >> 3, k0 = (t & 7) * 4;
      *(float4*)&sa[row * 36 + k0] =
          *(const float4*)&asrc[(size_t)(base + row) * C + kg + k0];
    }
    {  // stage W chunk: 32 k x 128 cols; each thread four float4
      int k = t >> 3, c0 = (t & 7) * 16;
      const float* g = &wsrc[(size_t)(kg + k) * H + c0];
      float* l = &sw[k * 132 + c0];
#pragma unroll
      for (int m = 0; m < 4; ++m) *(float4*)(l + m * 4) = *(const float4*)(g + m * 4);
    }
    __syncthreads();
#pragma unroll
    for (int k4 = 0; k4 < 32; k4 += 4) {
      float4 av[4];
      av[0] = *(const float4*)&sa[(ty)      * 36 + k4];
      av[1] = *(const float4*)&sa[(ty + 8)  * 36 + k4];
      av[2] = *(const float4*)&sa[(ty + 16) * 36 + k4];
      av[3] = *(const float4*)&sa[(ty + 24) * 36 + k4];
#pragma unroll
      for (int kk = 0; kk < 4; ++kk) {
        float4 wv = *(const float4*)&sw[(k4 + kk) * 132 + tx * 4];
#pragma unroll
        for (int j = 0; j < 4; ++j) {
          float a = ((const float*)&av[j])[kk];
          acc[j][0] += a * wv.x; acc[j][1] += a * wv.y;
          acc[j][2] += a * wv.z; acc[j][3] += a * wv.w;
        }
      }
    }
  }
  __syncthreads();
  float rn = 1.0f / sqrtf(s_norm);
  float4 p = *(const float4*)&pw[tx * 4];
#pragma unroll
  for (int j = 0; j < 4; ++j) {
    int row = base + ty + 8 * j;
    float4 o;
    o.x = fmaxf(acc[j][0], 0.f); o.y = fmaxf(acc[j][1], 0.f);
    o.z = fmaxf(acc[j][2], 0.f); o.w = fmaxf(acc[j][3], 0.f);
    *(float4*)&out[(size_t)row * H + tx * 4] = o;
    float d = o.x * p.x + o.y * p.y + o.z * p.z + o.w * p.w;
#pragma unroll
    for (int off = 1; off < 32; off <<= 1) d += __shfl_xor(d, off);
    if (tx == 0) {
      float s = tanhf(d * rn);
      unsigned kv = map_f2u(s);
      key[row] = kv;
      atomicAdd(&hist[kv >> 16], 1u);
    }
  }
}

// ---------------- select pass 1: find high-16 bin; self-clean hist ---------
__global__ void sel_scan1_kernel(unsigned* __restrict__ hist, unsigned* __restrict__ rs, int k) {
  __shared__ unsigned s[1024];
  int t = threadIdx.x;
  unsigned loc[64];
  unsigned sum = 0;
#pragma unroll
  for (int j = 0; j < 64; ++j) { loc[j] = hist[t * 64 + j]; sum += loc[j]; }
#pragma unroll
  for (int j = 0; j < 64; ++j) hist[t * 64 + j] = 0u;  // clean for pass 2
  s[t] = sum;
  __syncthreads();
  for (int off = 1; off < 1024; off <<= 1) {
    unsigned x = (t >= off) ? s[t - off] : 0u;
    __syncthreads();
    s[t] += x;
    __syncthreads();
  }
  unsigned total = s[1023];
  unsigned above = total - s[t];
  if (above < (unsigned)k && above + sum >= (unsigned)k) {
    unsigned cum = above;
    int b = 0; unsigned need = 0;
#pragma unroll
    for (int j = 63; j >= 0; --j) {
      unsigned c = loc[j];
      if (cum + c >= (unsigned)k) { b = t * 64 + j; need = (unsigned)k - cum; break; }
      cum += c;
    }
    rs[0] = (unsigned)b;
    rs[1] = need;
  }
}

__global__ void sel_hist2_kernel(const unsigned* __restrict__ key,
                                 const unsigned* __restrict__ rs,
                                 unsigned* __restrict__ hist, int N) {
  unsigned bhi = rs[0];
  for (int i = blockIdx.x * blockDim.x + threadIdx.x; i < N; i += gridDim.x * blockDim.x) {
    unsigned kv = key[i];
    if ((kv >> 16) == bhi) atomicAdd(&hist[kv & 0xFFFFu], 1u);
  }
}

// self-cleans hist (so next layer's score hist starts from zero)
__global__ void sel_scan2_kernel(unsigned* __restrict__ hist, unsigned* __restrict__ rs) {
  __shared__ unsigned s[1024];
  __shared__ unsigned sh_bhi, sh_need;
  int t = threadIdx.x;
  if (t == 0) { sh_bhi = rs[0]; sh_need = rs[1]; }
  __syncthreads();
  unsigned k = sh_need, bhi = sh_bhi;
  unsigned loc[64];
  unsigned sum = 0;
#pragma unroll
  for (int j = 0; j < 64; ++j) { loc[j] = hist[t * 64 + j]; sum += loc[j]; }
#pragma unroll
  for (int j = 0; j < 64; ++j) hist[t * 64 + j] = 0u;  // self-clean
  s[t] = sum;
  __syncthreads();
  for (int off = 1; off < 1024; off <<= 1) {
    unsigned x = (t >= off) ? s[t - off] : 0u;
    __syncthreads();
    s[t] += x;
    __syncthreads();
  }
  unsigned above = s[1023] - s[t];
  if (above < k && above + sum >= k) {
    unsigned cum = above;
    int b = 0; unsigned need = 0;
#pragma unroll
    for (int j = 63; j >= 0; --j) {
      unsigned c = loc[j];
      if (cum + c >= k) { b = t * 64 + j; need = k - cum; break; }
      cum += c;
    }
    rs[0] = (bhi << 16) | (unsigned)b;
    rs[1] = need;
    rs[2] = 0u;
    rs[3] = 0u;
  }
}

__global__ void sel_compact_kernel(const unsigned* __restrict__ key,
                                   unsigned* __restrict__ rs,
                                   int* __restrict__ perm, int N, int k) {
  unsigned T = rs[0];
  unsigned need = rs[1];
  int base = k - (int)need;
  for (int i = blockIdx.x * blockDim.x + threadIdx.x; i < N; i += gridDim.x * blockDim.x) {
    unsigned kv = key[i];
    if (kv > T) {
      unsigned p = atomicAdd(&rs[2], 1u);
      perm[p] = i;
    } else if (kv == T) {
      unsigned t = atomicAdd(&rs[3], 1u);
      if (t < need) perm[base + (int)t] = i;
    }
  }
}

// ---------------- pool gather + gate + pos + readout + knn cell count ------
template<int ROWS, bool CELLS>
__global__ void pool_readout_kernel(const float* __restrict__ xin,
                                    const unsigned* __restrict__ key,
                                    const int* __restrict__ perm,
                                    const float* __restrict__ posin,
                                    float* __restrict__ xout, float* __restrict__ posout,
                                    float* __restrict__ pmax, float* __restrict__ psum,
                                    unsigned* __restrict__ kcnt, int* __restrict__ kcid) {
  int f = threadIdx.x;  // 128
  int base = blockIdx.x * ROWS;
  float mx = -INFINITY, sm = 0.f;
  for (int r = 0; r < ROWS; ++r) {
    int p = perm[base + r];
    float sc = map_u2f(key[p]);
    float v = xin[(size_t)p * H + f] * sc;
    xout[(size_t)(base + r) * H + f] = v;
    mx = fmaxf(mx, v);
    sm += v;
    if (f < 2) posout[(base + r) * 2 + f] = posin[p * 2 + f];
    if (CELLS && f == 0) {
      float px = posin[p * 2], py = posin[p * 2 + 1];
      int cx = min(max((int)(px * (float)G), 0), G - 1);
      int cy = min(max((int)(py * (float)G), 0), G - 1);
      int c = cy * G + cx;
      kcid[base + r] = c;
      atomicAdd(&kcnt[c], 1u);
    }
  }
  pmax[blockIdx.x * H + f] = mx;
  psum[blockIdx.x * H + f] = sm;
}

// 256 blocks x 128 threads: local reduce over nPart/256 partials, then one
// atomicMax (monotonic uint) + one atomicAdd (float) per column per block.
__global__ void readout_atomic_kernel(const float* __restrict__ pmax,
                                      const float* __restrict__ psum,
                                      unsigned* __restrict__ ham,
                                      float* __restrict__ has, int nPart) {
  int f = threadIdx.x;  // 128
  int per = nPart / gridDim.x;
  int b0 = blockIdx.x * per;
  float mx = -INFINITY, sm = 0.f;
  for (int b = b0; b < b0 + per; ++b) {
    mx = fmaxf(mx, pmax[b * H + f]);
    sm += psum[b * H + f];
  }
  atomicMax(&ham[f], map_f2u(mx));
  atomicAdd(&has[f], sm);
}

// ---------------- KNN via uniform grid (exact) -----------------------------
__global__ void grid_scatter_kernel(const int* __restrict__ cellId,
                                    unsigned* __restrict__ cursor,
                                    int* __restrict__ cellPts, int M) {
  int i = blockIdx.x * blockDim.x + threadIdx.x;
  if (i >= M) return;
  unsigned slot = atomicAdd(&cursor[cellId[i]], 1u);
  cellPts[slot] = i;
}

// queries processed in cell-sorted order for wave coherence + cache locality
template<int K>
__global__ void knn_grid_kernel(const float* __restrict__ pos,
                                const unsigned* __restrict__ pre,
                                const int* __restrict__ cellPts,
                                int* __restrict__ nbr, int M) {
  int s_ = blockIdx.x * blockDim.x + threadIdx.x;
  if (s_ >= M) return;
  int i = cellPts[s_];
  float2 q = reinterpret_cast<const float2*>(pos)[i];
  int cx = min(max((int)(q.x * (float)G), 0), G - 1);
  int cy = min(max((int)(q.y * (float)G), 0), G - 1);
  float bd[K];
  int   bi_[K];
#pragma unroll
  for (int t = 0; t < K; ++t) { bd[t] = INFINITY; bi_[t] = -1; }
  float worst = INFINITY;
  constexpr float cw = 1.0f / (float)G;
  for (int r = 0; r <= G; ++r) {
    if (r > 0) {
      float dl = q.x - (float)(cx - r + 1) * cw;
      float dr = (float)(cx + r) * cw - q.x;
      float db = q.y - (float)(cy - r + 1) * cw;
      float dt = (float)(cy + r) * cw - q.y;
      float m = fminf(fminf(dl, dr), fminf(db, dt));
      if (worst <= m * m) break;
    }
    int xlo = max(cx - r, 0), xhi = min(cx + r, G - 1);
    int ylo = max(cy - r, 0), yhi = min(cy + r, G - 1);
    for (int yy = ylo; yy <= yhi; ++yy) {
      bool yedge = (yy == cy - r) || (yy == cy + r);
      for (int xx = xlo; xx <= xhi; ++xx) {
        if (!yedge && xx != cx - r && xx != cx + r) continue;
        int c = yy * G + xx;
        unsigned s0 = pre[c], s1 = pre[c + 1];
        for (unsigned s = s0; s < s1; ++s) {
          int j = cellPts[s];
          float2 pj = reinterpret_cast<const float2*>(pos)[j];
          float dx = q.x - pj.x, dy = q.y - pj.y;
          float d = dx * dx + dy * dy;
          if (d < worst && j != i) {
            int ws = 0; float wm = bd[0];
#pragma unroll
            for (int t = 1; t < K; ++t) if (bd[t] > wm) { wm = bd[t]; ws = t; }
#pragma unroll
            for (int t = 0; t < K; ++t) {
              bool hit = (t == ws);
              bd[t]  = hit ? d : bd[t];
              bi_[t] = hit ? j : bi_[t];
            }
            float nm = bd[0];
#pragma unroll
            for (int t = 1; t < K; ++t) nm = fmaxf(nm, bd[t]);
            worst = nm;
          }
        }
      }
    }
  }
#pragma unroll
  for (int t = 0; t < K; ++t) nbr[(size_t)i * K + t] = bi_[t];
}

template<int K>
__global__ void knn_agg_kernel(const float* __restrict__ x, const int* __restrict__ nbr,
                               float* __restrict__ agg, int M) {
  int gid = blockIdx.x * blockDim.x + threadIdx.x;
  int i = gid >> 7, f = gid & 127;
  if (i >= M) return;
  float s = 0.f;
#pragma unroll
  for (int j = 0; j < K; ++j) s += x[(size_t)nbr[(size_t)i * K + j] * H + f];
  agg[(size_t)i * H + f] = s;
}

// ---------------- final MLP head (tiny) ------------------------------------
// ham: [3][128] monotonic-uint maxes; has: [3][128] float sums.
__global__ void mlp_kernel(const unsigned* __restrict__ ham,
                           const float* __restrict__ has,
                           const float* __restrict__ w1, const float* __restrict__ b1,
                           const float* __restrict__ w2, const float* __restrict__ b2,
                           const float* __restrict__ w3, const float* __restrict__ b3,
                           float* __restrict__ out) {
  __shared__ float h[256], h1[128], h2[64];
  int t = threadIdx.x;
  if (t < 128) {
    h[t] = map_u2f(ham[t]) + map_u2f(ham[128 + t]) + map_u2f(ham[256 + t]);
  } else {
    int f = t - 128;
    h[t] = has[f] * (1.0f / (float)N1) + has[128 + f] * (1.0f / (float)N2)
         + has[256 + f] * (1.0f / (float)N3);
  }
  __syncthreads();
  if (t < 128) {
    float a = b1[t];
    for (int c = 0; c < 256; ++c) a += h[c] * w1[c * 128 + t];
    h1[t] = fmaxf(a, 0.f);
  }
  __syncthreads();
  if (t < 64) {
    float a = b2[t];
    for (int c = 0; c < 128; ++c) a += h1[c] * w2[c * 64 + t];
    h2[t] = fmaxf(a, 0.f);
  }
  __syncthreads();
  if (t < 10) {
    float a = b3[t];
    for (int c = 0; c < 64; ++c) a += h2[c] * w3[c * 10 + t];
    out[t] = a;
  }
}

}  // namespace

extern "C" void kernel_launch(void* const* d_in, const int* in_sizes, int n_in,
                              void* d_out, int out_size, void* d_ws, size_t ws_size,
                              hipStream_t stream) {
  const float* X     = (const float*)d_in[0];   // [N0, C0]
  const float* POS0  = (const float*)d_in[1];   // [N0, 2]
  const int*   EI    = (const int*)d_in[2];     // [2, E0]
  const float* Wrel0 = (const float*)d_in[4];
  const float* brel0 = (const float*)d_in[5];
  const float* Wroot0= (const float*)d_in[6];
  const float* pw0   = (const float*)d_in[7];
  const float* Wrel1 = (const float*)d_in[8];
  const float* brel1 = (const float*)d_in[9];
  const float* Wroot1= (const float*)d_in[10];
  const float* pw1   = (const float*)d_in[11];
  const float* Wrel2 = (const float*)d_in[12];
  const float* brel2 = (const float*)d_in[13];
  const float* Wroot2= (const float*)d_in[14];
  const float* pw2   = (const float*)d_in[15];
  const float* L1W   = (const float*)d_in[16];
  const float* L1B   = (const float*)d_in[17];
  const float* L2W   = (const float*)d_in[18];
  const float* L2B   = (const float*)d_in[19];
  const float* L3W   = (const float*)d_in[20];
  const float* L3B   = (const float*)d_in[21];

  // ---- workspace layout (bytes) ----
  char* w = (char*)d_ws;
  float*    A    = (float*)(w);                     // 32 MiB: conv out / agg / scratch
  float*    B    = (float*)(w + 33554432u);         // 16 MiB: agg0 / pooled x
  float*    P1   = (float*)(w + 50331648u);         // 256 KB
  float*    P2   = (float*)(w + 50593792u);         // 128 KB
  int*      NBR  = (int*)  (w + 50724864u);         // 768 KB
  unsigned* KY   = (unsigned*)(w + 51511296u);      // 256 KB keys (+ knn pre/cur alias)
  int*      PM   = (int*)  (w + 51773440u);         // 128 KB perm
  unsigned* RS   = (unsigned*)(w + 51904512u);      // 4 KB select state
  unsigned* KCNT = (unsigned*)(w + 51908608u);      // 16 KB knn cell counts   \ zeroed
  unsigned* HBUF = (unsigned*)(w + 51924992u);      // 256 KB select hists      | in one
  unsigned* ECNT = (unsigned*)(w + 52187136u);      // 256 KB edge counts/cellId| fill
  unsigned* HAM  = (unsigned*)(w + 52449280u);      // 1.5 KB [3][128] max accum| (544K)
  float*    HAS  = (float*)(w + 52450816u);         // 1.5 KB [3][128] sum accum/
  unsigned* EPRE = (unsigned*)(w + 52453376u);      // 256 KB + 4
  unsigned* ECUR = (unsigned*)(w + 52715776u);      // 256 KB
  float*    RPm  = (float*)(w + 52977920u);         // 1 MB readout partial max (<=2048)
  float*    RPs  = (float*)(w + 54026496u);         // 1 MB readout partial sum

  int*      ES    = (int*)A;                        // 2 MB sorted edge src (layer0)
  unsigned* KPRE  = KY;                             // 16 KB + 4 (knn prefix)
  unsigned* KCUR  = KY + 4160;                      // 16 KB (knn cursor)
  int*      KCID  = (int*)ECNT;                     // knn cell ids (edge bufs dead)
  int*      KCPTS = (int*)A;                        // cell-sorted point list

  float* OUT = (float*)d_out;

  // ==================== layer 0 ====================
  // one contiguous zero fill: KCNT(16K)+HBUF(256K)+ECNT(256K)+HAM/HAS(4K) = 532 KB
  fill_zero_kernel<<<532, 256, 0, stream>>>((float*)KCNT, 136192);

  edge_count_kernel<<<E0 / 256, 256, 0, stream>>>(EI + E0, ECNT);
  scan_kernel<64><<<1, 1024, 0, stream>>>(ECNT, EPRE, ECUR);
  edge_scatter_kernel<<<E0 / 256, 256, 0, stream>>>(EI, EI + E0, ECUR, ES);
  gather_agg_kernel<<<(N0 * 64) / 256, 256, 0, stream>>>(X, EPRE, ES, B);

  conv_score_kernel<C0><<<N0 / 32, 256, 0, stream>>>(B, X, Wrel0, brel0, Wroot0,
                                                     pw0, A, KY, HBUF);
  sel_scan1_kernel<<<1, 1024, 0, stream>>>(HBUF, RS, N1);
  sel_hist2_kernel<<<256, 256, 0, stream>>>(KY, RS, HBUF, N0);
  sel_scan2_kernel<<<1, 1024, 0, stream>>>(HBUF, RS);
  sel_compact_kernel<<<256, 256, 0, stream>>>(KY, RS, PM, N0, N1);

  pool_readout_kernel<16, true><<<N1 / 16, 128, 0, stream>>>(
      A, KY, PM, POS0, B, P1, RPm, RPs, KCNT, KCID);
  readout_atomic_kernel<<<256, 128, 0, stream>>>(RPm, RPs, HAM, HAS, N1 / 16);

  scan_kernel<4><<<1, 1024, 0, stream>>>(KCNT, KPRE, KCUR);
  grid_scatter_kernel<<<N1 / 256, 256, 0, stream>>>(KCID, KCUR, KCPTS, N1);
  knn_grid_kernel<6><<<N1 / 64, 64, 0, stream>>>(P1, KPRE, KCPTS, NBR, N1);

  // ==================== layer 1 ====================
  float* AGG1 = A;                       // [N1, H]
  float* CV1  = A + (size_t)N1 * H;      // [N1, H]
  knn_agg_kernel<6><<<(N1 * H) / 256, 256, 0, stream>>>(B, NBR, AGG1, N1);
  conv_score_kernel<H><<<N1 / 32, 256, 0, stream>>>(AGG1, B, Wrel1, brel1, Wroot1,
                                                    pw1, CV1, KY, HBUF);
  sel_scan1_kernel<<<1, 1024, 0, stream>>>(HBUF, RS, N2);
  sel_hist2_kernel<<<256, 256, 0, stream>>>(KY, RS, HBUF, N1);
  sel_scan2_kernel<<<1, 1024, 0, stream>>>(HBUF, RS);
  sel_compact_kernel<<<256, 256, 0, stream>>>(KY, RS, PM, N1, N2);

  pool_readout_kernel<16, true><<<N2 / 16, 128, 0, stream>>>(
      CV1, KY, PM, P1, B, P2, RPm, RPs, KCNT, KCID);
  readout_atomic_kernel<<<256, 128, 0, stream>>>(RPm, RPs, HAM + 128, HAS + 128, N2 / 16);

  scan_kernel<4><<<1, 1024, 0, stream>>>(KCNT, KPRE, KCUR);
  grid_scatter_kernel<<<N2 / 256, 256, 0, stream>>>(KCID, KCUR, KCPTS, N2);
  knn_grid_kernel<8><<<N2 / 64, 64, 0, stream>>>(P2, KPRE, KCPTS, NBR, N2);

  // ==================== layer 2 ====================
  float* AGG2 = A;                       // [N2, H]
  float* CV2  = A + (size_t)N2 * H;      // [N2, H]
  knn_agg_kernel<8><<<(N2 * H) / 256, 256, 0, stream>>>(B, NBR, AGG2, N2);
  conv_score_kernel<H><<<N2 / 32, 256, 0, stream>>>(AGG2, B, Wrel2, brel2, Wroot2,
                                                    pw2, CV2, KY, HBUF);
  sel_scan1_kernel<<<1, 1024, 0, stream>>>(HBUF, RS, N3);
  sel_hist2_kernel<<<256, 256, 0, stream>>>(KY, RS, HBUF, N2);
  sel_scan2_kernel<<<1, 1024, 0, stream>>>(HBUF, RS);
  sel_compact_kernel<<<256, 256, 0, stream>>>(KY, RS, PM, N2, N3);

  // last pool's pos output is never consumed; P1 is dead scratch here
  pool_readout_kernel<16, false><<<N3 / 16, 128, 0, stream>>>(
      CV2, KY, PM, P2, B, P1, RPm, RPs, KCNT, KCID);
  readout_atomic_kernel<<<256, 128, 0, stream>>>(RPm, RPs, HAM + 256, HAS + 256, N3 / 16);

  // ==================== head ====================
  mlp_kernel<<<1, 256, 0, stream>>>(HAM, HAS, L1W, L1B, L2W, L2B, L3W, L3B, OUT);
}